// Round 7
// baseline (198.781 us; speedup 1.0000x reference)
//
#include <hip/hip_runtime.h>
#include <cstdint>

#define D_MODEL 1024
#define N_HEADS 16
#define D_K     64
#define BATCH   2
#define SEQ     2048
#define TOKENS  (BATCH * SEQ)
#define LN_EPS  1e-5f
// 1/sqrt(D_K) * log2(e), folded into Q so softmax uses exp2 directly
#define QSCALE  0.18033688011112042f

typedef __bf16 bf16x8 __attribute__((ext_vector_type(8)));
typedef float  floatx4  __attribute__((ext_vector_type(4)));
typedef float  floatx16 __attribute__((ext_vector_type(16)));
typedef float  floatx2  __attribute__((ext_vector_type(2)));
typedef unsigned uint32x2 __attribute__((ext_vector_type(2)));

__device__ __forceinline__ unsigned short f2bf(float f) {
  union { float f; unsigned u; } v; v.f = f;
  unsigned r = v.u + 0x7fffu + ((v.u >> 16) & 1u);
  return (unsigned short)(r >> 16);
}
// pack two f32 -> two bf16 (truncate) in ONE v_perm_b32
__device__ __forceinline__ unsigned pk2bf(float hi, float lo) {
  union { float f; unsigned u; } a, b;
  a.f = hi; b.f = lo;
  return __builtin_amdgcn_perm(a.u, b.u, 0x07060302u);
}

// async global -> LDS, 16 B per lane; LDS dest = wave-uniform base + lane*16
__device__ __forceinline__ void cp16(void* lds, const void* g) {
  __builtin_amdgcn_global_load_lds(
      (__attribute__((address_space(1))) void*)g,
      (__attribute__((address_space(3))) void*)lds, 16, 0, 0);
}

// v_permlane32_swap_b32: r.x = {a[0:31], b[0:31]}, r.y = {a[32:63], b[32:63]}
// Pure VALU cross-half exchange (replaces ds_bpermute-based __shfl_xor(x,32)).
__device__ __forceinline__ uint32x2 pswap(unsigned a, unsigned b) {
  return __builtin_amdgcn_permlane32_swap(a, b, false, false);
}

// ---------------- prep: weight fp32->bf16 (blocks 0..4095) + LN (4096..8191)
__global__ __launch_bounds__(256) void prep_kernel(
    const float* __restrict__ h, const float* __restrict__ w0,
    const float* __restrict__ w1, const float* __restrict__ w2,
    const float* __restrict__ w3, const float* __restrict__ lw,
    const float* __restrict__ lb, unsigned short* __restrict__ Wcat,
    unsigned short* __restrict__ hn) {
  if (blockIdx.x < 4096) {
    int wsel = blockIdx.x >> 10;
    const float* s = (wsel == 0) ? w0 : (wsel == 1) ? w1 : (wsel == 2) ? w2 : w3;
    unsigned short* d = Wcat + ((size_t)wsel << 20);
    int i = ((blockIdx.x & 1023) << 8) + threadIdx.x;
    float4 v = reinterpret_cast<const float4*>(s)[i];
    ushort4 o;
    o.x = f2bf(v.x); o.y = f2bf(v.y); o.z = f2bf(v.z); o.w = f2bf(v.w);
    reinterpret_cast<ushort4*>(d)[i] = o;
    return;
  }
  int row = blockIdx.x - 4096;
  const float* x = h + (size_t)row * D_MODEL;
  float4 v = reinterpret_cast<const float4*>(x)[threadIdx.x];
  float s  = v.x + v.y + v.z + v.w;
  float s2 = v.x * v.x + v.y * v.y + v.z * v.z + v.w * v.w;
  for (int m = 1; m < 64; m <<= 1) {
    s  += __shfl_xor(s, m);
    s2 += __shfl_xor(s2, m);
  }
  __shared__ float ls[4], ls2[4];
  int wave = threadIdx.x >> 6;
  if ((threadIdx.x & 63) == 0) { ls[wave] = s; ls2[wave] = s2; }
  __syncthreads();
  s  = ls[0] + ls[1] + ls[2] + ls[3];
  s2 = ls2[0] + ls2[1] + ls2[2] + ls2[3];
  float mu  = s * (1.0f / D_MODEL);
  float var = s2 * (1.0f / D_MODEL) - mu * mu;
  float rs  = rsqrtf(var + LN_EPS);
  float4 wv = reinterpret_cast<const float4*>(lw)[threadIdx.x];
  float4 bv = reinterpret_cast<const float4*>(lb)[threadIdx.x];
  ushort4 o;
  o.x = f2bf((v.x - mu) * rs * wv.x + bv.x);
  o.y = f2bf((v.y - mu) * rs * wv.y + bv.y);
  o.z = f2bf((v.z - mu) * rs * wv.z + bv.z);
  o.w = f2bf((v.w - mu) * rs * wv.w + bv.w);
  reinterpret_cast<ushort4*>(hn + (size_t)row * D_MODEL)[threadIdx.x] = o;
}

// ---------------- fused QKV GEMM: [4096,1024] @ [3072,1024]^T -------------
// BM=256 BN=192 BK=64, 512 thr (8 waves, wave tile 64x96), double-buffered
// LDS (112 KB, 1 block/CU), 2-phase prefetch, grid 16x16 = 1 block/CU.
__global__ __launch_bounds__(512, 2) void gemm_qkv_kernel(
    const unsigned short* __restrict__ A, const unsigned short* __restrict__ Wcat,
    const float* __restrict__ bq, const float* __restrict__ bk,
    const float* __restrict__ bv,
    unsigned short* __restrict__ QK, unsigned short* __restrict__ VtG) {
  __shared__ unsigned short As[2][256 * 64];  // 64 KB
  __shared__ unsigned short Bs[2][192 * 64];  // 48 KB

  const int tid  = threadIdx.x;
  const int w    = tid >> 6;        // 0..7
  const int lane = tid & 63;
  const int l15  = lane & 15;
  const int quad = lane >> 4;
  const int sw   = l15 & 7;
  const int wrow = (w >> 1) * 64;   // 0,64,128,192
  const int wcol = (w & 1) * 96;    // 0,96

  // XCD-aware bijective swizzle (grid 256 = 8 XCDs x 32 contiguous blocks)
  const int flat  = blockIdx.x + (blockIdx.y << 4);
  const int swzid = ((flat & 7) << 5) + (flat >> 3);
  const int bm = (swzid >> 4) * 256;
  const int bn = (swzid & 15) * 192;

  const int srow = tid >> 3;                        // 0..63
  const int swzc = (((tid & 7) ^ (srow & 7)) * 8);  // swizzled source granule
  const unsigned short* ga = A    + (size_t)(bm + srow) * 1024 + swzc;
  const unsigned short* gb = Wcat + (size_t)(bn + srow) * 1024 + swzc;

  floatx4 acc[4][6];
#pragma unroll
  for (int i = 0; i < 4; ++i)
#pragma unroll
    for (int j = 0; j < 6; ++j) acc[i][j] = {0.f, 0.f, 0.f, 0.f};

  auto stage = [&](int k0, int b) {
    unsigned short* asl = &As[b][0] + w * 512;
    unsigned short* bsl = &Bs[b][0] + w * 512;
#pragma unroll
    for (int i = 0; i < 4; ++i) cp16(asl + i * 4096, ga + (size_t)i * 64 * 1024 + k0);
#pragma unroll
    for (int i = 0; i < 3; ++i) cp16(bsl + i * 4096, gb + (size_t)i * 64 * 1024 + k0);
  };

  stage(0, 0);

  for (int t = 0; t < 16; ++t) {
    __syncthreads();
    if (t + 1 < 16) stage((t + 1) * 64, (t + 1) & 1);
    const unsigned short* Ab = &As[t & 1][0];
    const unsigned short* Bb = &Bs[t & 1][0];
#pragma unroll
    for (int kb = 0; kb < 2; ++kb) {
      bf16x8 af[4], bfr[6];
#pragma unroll
      for (int mi = 0; mi < 4; ++mi)
        af[mi] = *reinterpret_cast<const bf16x8*>(
            Ab + (wrow + mi * 16 + l15) * 64 + (((kb * 4 + quad) ^ sw) * 8));
#pragma unroll
      for (int ni = 0; ni < 6; ++ni)
        bfr[ni] = *reinterpret_cast<const bf16x8*>(
            Bb + (wcol + ni * 16 + l15) * 64 + (((kb * 4 + quad) ^ sw) * 8));
#pragma unroll
      for (int mi = 0; mi < 4; ++mi)
#pragma unroll
        for (int ni = 0; ni < 6; ++ni)
          acc[mi][ni] = __builtin_amdgcn_mfma_f32_16x16x32_bf16(af[mi], bfr[ni], acc[mi][ni], 0, 0, 0);
    }
  }

  // epilogue: per-16-col fragment Q/K/V select (wave-uniform)
#pragma unroll
  for (int mi = 0; mi < 4; ++mi) {
    const int row0 = bm + wrow + mi * 16 + quad * 4;
#pragma unroll
    for (int ni = 0; ni < 6; ++ni) {
      const int cb  = bn + wcol + ni * 16;   // uniform per (wave, ni)
      const int col = cb + l15;
      if (cb < 1024) {
        float bb = bq[col];
#pragma unroll
        for (int r = 0; r < 4; ++r)
          QK[(size_t)(row0 + r) * 2048 + col] = f2bf((acc[mi][ni][r] + bb) * QSCALE);
      } else if (cb < 2048) {
        float bb = bk[col - 1024];
#pragma unroll
        for (int r = 0; r < 4; ++r)
          QK[(size_t)(row0 + r) * 2048 + col] = f2bf(acc[mi][ni][r] + bb);
      } else {
        int d = col - 2048;
        float bb = bv[d];
        ushort4 o;
        o.x = f2bf(acc[mi][ni][0] + bb);
        o.y = f2bf(acc[mi][ni][1] + bb);
        o.z = f2bf(acc[mi][ni][2] + bb);
        o.w = f2bf(acc[mi][ni][3] + bb);
        *reinterpret_cast<ushort4*>(VtG + (size_t)d * 4096 + row0) = o;
      }
    }
  }
}

// ---------------- output GEMM: Obuf @ Wo^T + bo + resid -> fp32 -----------
// 2-phase prefetch (single barrier per K-step, double-buffered LDS).
__global__ __launch_bounds__(256) void gemm_out_kernel(
    const unsigned short* __restrict__ A, const unsigned short* __restrict__ Bt,
    const float* __restrict__ bo, const float* __restrict__ resid,
    float* __restrict__ out) {
  __shared__ unsigned short As[2][128 * 64];  // 32 KB
  __shared__ unsigned short Bs[2][64 * 64];   // 16 KB

  const int tid  = threadIdx.x;
  const int w    = tid >> 6;
  const int lane = tid & 63;
  const int l15  = lane & 15;
  const int quad = lane >> 4;
  const int sw   = l15 & 7;
  const int wm = (w >> 1) * 64;
  const int wn = (w & 1) * 32;
  const int bm = blockIdx.y * 128;
  const int bn = blockIdx.x * 64;

  const int srow = tid >> 3;
  const int swzc = (((tid & 7) ^ (srow & 7)) * 8);
  const unsigned short* ga = A  + (size_t)(bm + srow) * 1024 + swzc;
  const unsigned short* gb = Bt + (size_t)(bn + srow) * 1024 + swzc;

  floatx4 acc[4][2];
  for (int i = 0; i < 4; ++i)
    for (int j = 0; j < 2; ++j) acc[i][j] = {0.f, 0.f, 0.f, 0.f};

  auto stage = [&](int k0, int b) {
    unsigned short* asl = &As[b][0] + w * 512;
    unsigned short* bsl = &Bs[b][0] + w * 512;
#pragma unroll
    for (int i = 0; i < 4; ++i) cp16(asl + i * 2048, ga + (size_t)i * 32 * 1024 + k0);
#pragma unroll
    for (int i = 0; i < 2; ++i) cp16(bsl + i * 2048, gb + (size_t)i * 32 * 1024 + k0);
  };

  stage(0, 0);

  for (int t = 0; t < 16; ++t) {
    __syncthreads();                      // tile t staged, tile t-1 reads done
    if (t + 1 < 16) stage((t + 1) * 64, (t + 1) & 1);  // overlap with compute
    const unsigned short* Ab = &As[t & 1][0];
    const unsigned short* Bb = &Bs[t & 1][0];
#pragma unroll
    for (int kb = 0; kb < 2; ++kb) {
      bf16x8 af[4], bfr[2];
#pragma unroll
      for (int mi = 0; mi < 4; ++mi)
        af[mi] = *reinterpret_cast<const bf16x8*>(
            Ab + (wm + mi * 16 + l15) * 64 + (((kb * 4 + quad) ^ sw) * 8));
#pragma unroll
      for (int ni = 0; ni < 2; ++ni)
        bfr[ni] = *reinterpret_cast<const bf16x8*>(
            Bb + (wn + ni * 16 + l15) * 64 + (((kb * 4 + quad) ^ sw) * 8));
#pragma unroll
      for (int mi = 0; mi < 4; ++mi)
#pragma unroll
        for (int ni = 0; ni < 2; ++ni)
          acc[mi][ni] = __builtin_amdgcn_mfma_f32_16x16x32_bf16(af[mi], bfr[ni], acc[mi][ni], 0, 0, 0);
    }
  }

#pragma unroll
  for (int mi = 0; mi < 4; ++mi)
#pragma unroll
    for (int ni = 0; ni < 2; ++ni) {
      int col = bn + wn + ni * 16 + l15;
      float bb = bo[col];
#pragma unroll
      for (int r = 0; r < 4; ++r) {
        int row = bm + wm + mi * 16 + quad * 4 + r;
        size_t idx = (size_t)row * 1024 + col;
        out[idx] = acc[mi][ni][r] + bb + resid[idx];
      }
    }
}

// ---------------- flash attention: grid (H, S/128, B), 512 thr ------------
// R4 structure + R7: T5 setprio around MFMA clusters. Mechanism: each CU
// hosts 2 INDEPENDENT blocks (unshared barriers) -> each SIMD has 2 waves
// of each block at different phases; setprio(1) lets MFMA-phase waves win
// issue arbitration over softmax-phase waves of the other block (m191).
// Row-sum tree via float2 (v_pk_add_f32): 7 pk-adds + 1 scalar vs 15 scalar.
__global__ __launch_bounds__(512, 4) void attn_kernel(
    const unsigned short* __restrict__ QK, const unsigned short* __restrict__ VtG,
    unsigned short* __restrict__ O) {
  __shared__ unsigned short Ks[2][128 * 64];  // [key][d]  swizzled
  __shared__ unsigned short Vs[2][64 * 128];  // [d][key]  swizzled

  const int tid  = threadIdx.x;
  const int w    = tid >> 6;     // 0..7
  const int wq   = w & 3;        // q sub-tile
  const int kb0  = (w >> 2) * 2; // key-half: kb in {kb0, kb0+1}
  const int lane = tid & 63;
  const int l31  = lane & 31;
  const int h    = lane >> 5;
  const int rsw  = (l31 & 7) ^ ((l31 >> 3) << 1);  // read swizzle

  const int hh = blockIdx.x, qt = blockIdx.y, bz = blockIdx.z;
  const int tq0  = bz * SEQ + qt * 128;
  const int hoff = hh * 64;

  // Q B-frags: n=q=lane&31, k = kd*16 + h*8 + j
  bf16x8 qf[4];
  {
    const unsigned short* qp =
        QK + (size_t)(tq0 + wq * 32 + l31) * 2048 + hoff + h * 8;
#pragma unroll
    for (int kd = 0; kd < 4; ++kd)
      qf[kd] = *reinterpret_cast<const bf16x8*>(qp + kd * 16);
  }

  floatx16 oacc[2];
#pragma unroll
  for (int db = 0; db < 2; ++db)
#pragma unroll
    for (int r = 0; r < 16; ++r) oacc[db][r] = 0.f;
  float lsum = 0.f;

  // staging addresses (512 threads: K rows tid>>3 in 0..63, V rows tid>>4 in 0..31)
  const unsigned short* kg = QK + 1024 + hoff
      + (size_t)(bz * SEQ + (tid >> 3)) * 2048
      + (((tid & 7) ^ ((tid >> 3) & 7) ^ ((w & 3) << 1)) * 8);
  const unsigned short* vg = VtG
      + (size_t)(hoff + (tid >> 4)) * 4096 + bz * SEQ
      + (((tid & 15) ^ ((tid >> 4) & 7) ^ (((w >> 1) & 3) << 1)) * 8);

  auto stage = [&](int kt, int b) {
    const unsigned short* kgi = kg + (size_t)(kt * 128) * 2048;
    const unsigned short* vgi = vg + kt * 128;
    unsigned short* ksl = Ks[b] + w * 512;
    unsigned short* vsl = Vs[b] + w * 512;
#pragma unroll
    for (int i = 0; i < 2; ++i) cp16(ksl + i * 4096, kgi + (size_t)(i * 64) * 2048);
#pragma unroll
    for (int i = 0; i < 2; ++i) cp16(vsl + i * 4096, vgi + (size_t)(i * 32) * 4096);
  };

  stage(0, 0);

  for (int kt = 0; kt < SEQ / 128; ++kt) {
    __syncthreads();
    if (kt + 1 < SEQ / 128) stage(kt + 1, (kt + 1) & 1);
    const unsigned short* Kb = Ks[kt & 1];
    const unsigned short* Vb = Vs[kt & 1];

    // S^T for this wave's 2 key-blocks of 32, K-dim 4 chunks of 16
    floatx16 ss[2];
#pragma unroll
    for (int kk = 0; kk < 2; ++kk)
#pragma unroll
      for (int r = 0; r < 16; ++r) ss[kk][r] = 0.f;
    __builtin_amdgcn_s_setprio(1);
#pragma unroll
    for (int kk = 0; kk < 2; ++kk) {
      const int kb = kb0 + kk;
      const unsigned short* krow = Kb + (kb * 32 + l31) * 64;
#pragma unroll
      for (int kd = 0; kd < 4; ++kd) {
        bf16x8 kf = *reinterpret_cast<const bf16x8*>(
            krow + (((kd * 2 + h) ^ rsw) * 8));
        ss[kk] = __builtin_amdgcn_mfma_f32_32x32x16_bf16(kf, qf[kd], ss[kk], 0, 0, 0);
      }
    }
    __builtin_amdgcn_s_setprio(0);

    // per key-block: exp2, row-sum, build PV B-frags in-register, PV MFMAs
#pragma unroll
    for (int kk = 0; kk < 2; ++kk) {
      const int kb = kb0 + kk;
      float e[16];
#pragma unroll
      for (int r = 0; r < 16; ++r) e[r] = __builtin_amdgcn_exp2f(ss[kk][r]);
      // packed row-sum tree: 7 v_pk_add_f32 + 1 scalar add
      floatx2 a0 = {e[0], e[1]},   a1 = {e[2], e[3]},
              a2 = {e[4], e[5]},   a3 = {e[6], e[7]},
              a4 = {e[8], e[9]},   a5 = {e[10], e[11]},
              a6 = {e[12], e[13]}, a7 = {e[14], e[15]};
      floatx2 b0 = a0 + a1, b1 = a2 + a3, b2 = a4 + a5, b3 = a6 + a7;
      floatx2 c0 = b0 + b1, c1 = b2 + b3;
      floatx2 d2 = c0 + c1;
      float bs = d2.x + d2.y;
      {  // cross-half row-sum: bs += bs[lane^32], via permlane (no LDS)
        union { float f; unsigned u; } bu; bu.f = bs;
        uint32x2 br = pswap(bu.u, bu.u);
        union { unsigned u; float f; } b0u, b1u;
        b0u.u = br.x; b1u.u = br.y;
        bs = b0u.f + b1u.f;
      }
      lsum += bs;
      unsigned p[8];
#pragma unroll
      for (int i = 0; i < 8; ++i) p[i] = pk2bf(e[2 * i + 1], e[2 * i]);

#pragma unroll
      for (int sub = 0; sub < 2; ++sub) {
        uint32x2 r0 = pswap(p[sub * 4 + 0], p[sub * 4 + 2]);
        uint32x2 r1 = pswap(p[sub * 4 + 1], p[sub * 4 + 3]);
        union { unsigned u[4]; bf16x8 v; } pf;
        pf.u[0] = r0.x;
        pf.u[1] = r1.x;
        pf.u[2] = r0.y;
        pf.u[3] = r1.y;
        __builtin_amdgcn_s_setprio(1);
#pragma unroll
        for (int db = 0; db < 2; ++db) {
          bf16x8 vf = *reinterpret_cast<const bf16x8*>(
              Vb + (db * 32 + l31) * 128 + (((kb * 4 + sub * 2 + h) ^ rsw) * 8));
          oacc[db] = __builtin_amdgcn_mfma_f32_32x32x16_bf16(vf, pf.v, oacc[db], 0, 0, 0);
        }
        __builtin_amdgcn_s_setprio(0);
      }
    }
  }

  // ---- combine the two key-halves (additive: no max tracking) ----
  __syncthreads();  // all waves done reading K/V LDS
  float* osc = (float*)&Ks[0][0];  // 32 KB: [wq][lane][32] bank-rotated
  float* lsc = (float*)&Vs[0][0];  // 1 KB:  [wq][lane]
  if (w >= 4) {
    float* dst = osc + ((size_t)(wq * 64 + lane) * 32);
#pragma unroll
    for (int db = 0; db < 2; ++db)
#pragma unroll
      for (int r = 0; r < 16; ++r)
        dst[(db * 16 + r + lane) & 31] = oacc[db][r];
    lsc[wq * 64 + lane] = lsum;
  }
  __syncthreads();
  if (w < 4) {
    const float* src = osc + ((size_t)(wq * 64 + lane) * 32);
    lsum += lsc[wq * 64 + lane];
#pragma unroll
    for (int db = 0; db < 2; ++db)
#pragma unroll
      for (int r = 0; r < 16; ++r)
        oacc[db][r] += src[(db * 16 + r + lane) & 31];

    // finalize: lane holds O[q=wq*32+l31][d = db*32 + (r&3)+8*(r>>2)+4*h]
    float inv = 1.0f / lsum;
    unsigned short* ob = O + (size_t)(tq0 + wq * 32 + l31) * 1024 + hoff;
#pragma unroll
    for (int db = 0; db < 2; ++db)
#pragma unroll
      for (int rg = 0; rg < 4; ++rg) {
        int d0 = db * 32 + rg * 8 + h * 4;
        uint2 ov;
        ov.x = pk2bf(oacc[db][rg * 4 + 1] * inv, oacc[db][rg * 4 + 0] * inv);
        ov.y = pk2bf(oacc[db][rg * 4 + 3] * inv, oacc[db][rg * 4 + 2] * inv);
        *reinterpret_cast<uint2*>(ob + d0) = ov;
      }
  }
}

// ---------------- launch ---------------------------------------------------
extern "C" void kernel_launch(void* const* d_in, const int* in_sizes, int n_in,
                              void* d_out, int out_size, void* d_ws, size_t ws_size,
                              hipStream_t stream) {
  const float* h    = (const float*)d_in[0];
  const float* Wq   = (const float*)d_in[1];
  const float* bq   = (const float*)d_in[2];
  const float* Wk   = (const float*)d_in[3];
  const float* bk   = (const float*)d_in[4];
  const float* Wv   = (const float*)d_in[5];
  const float* bv   = (const float*)d_in[6];
  const float* Wo   = (const float*)d_in[7];
  const float* bo   = (const float*)d_in[8];
  const float* ln_w = (const float*)d_in[9];
  const float* ln_b = (const float*)d_in[10];
  float* out = (float*)d_out;

  unsigned short* ws = (unsigned short*)d_ws;
  const size_t WSZ = (size_t)1 << 20;
  unsigned short* Wcat = ws;                       // 4M shorts: Wq|Wk|Wv|Wo
  unsigned short* hn   = Wcat + 4 * WSZ;           // [4096][1024]
  unsigned short* QKb  = hn + (size_t)TOKENS * D_MODEL;        // [4096][2048]
  unsigned short* VtG  = QKb + (size_t)TOKENS * 2048;          // [1024][4096]
  unsigned short* Obuf = VtG + (size_t)D_MODEL * TOKENS;       // [4096][1024]

  prep_kernel<<<8192, 256, 0, stream>>>(h, Wq, Wk, Wv, Wo, ln_w, ln_b, Wcat, hn);

  gemm_qkv_kernel<<<dim3(16, 16), 512, 0, stream>>>(hn, Wcat, bq, bk, bv, QKb, VtG);

  attn_kernel<<<dim3(N_HEADS, SEQ / 128, BATCH), 512, 0, stream>>>(QKb, VtG, Obuf);

  gemm_out_kernel<<<dim3(16, 32), 256, 0, stream>>>(Obuf, Wcat + 3 * WSZ, bo, h, out);
}

// Round 8
// 196.117 us; speedup vs baseline: 1.0136x; 1.0136x over previous
//
#include <hip/hip_runtime.h>
#include <cstdint>

#define D_MODEL 1024
#define N_HEADS 16
#define D_K     64
#define BATCH   2
#define SEQ     2048
#define TOKENS  (BATCH * SEQ)
#define LN_EPS  1e-5f
// 1/sqrt(D_K) * log2(e), folded into Q so softmax uses exp2 directly
#define QSCALE  0.18033688011112042f

typedef __bf16 bf16x8 __attribute__((ext_vector_type(8)));
typedef float  floatx4  __attribute__((ext_vector_type(4)));
typedef float  floatx16 __attribute__((ext_vector_type(16)));
typedef float  floatx2  __attribute__((ext_vector_type(2)));
typedef unsigned uint32x2 __attribute__((ext_vector_type(2)));

__device__ __forceinline__ unsigned short f2bf(float f) {
  union { float f; unsigned u; } v; v.f = f;
  unsigned r = v.u + 0x7fffu + ((v.u >> 16) & 1u);
  return (unsigned short)(r >> 16);
}
// pack two f32 -> two bf16 (truncate) in ONE v_perm_b32
__device__ __forceinline__ unsigned pk2bf(float hi, float lo) {
  union { float f; unsigned u; } a, b;
  a.f = hi; b.f = lo;
  return __builtin_amdgcn_perm(a.u, b.u, 0x07060302u);
}

// async global -> LDS, 16 B per lane; LDS dest = wave-uniform base + lane*16
__device__ __forceinline__ void cp16(void* lds, const void* g) {
  __builtin_amdgcn_global_load_lds(
      (__attribute__((address_space(1))) void*)g,
      (__attribute__((address_space(3))) void*)lds, 16, 0, 0);
}

// v_permlane32_swap_b32: r.x = {a[0:31], b[0:31]}, r.y = {a[32:63], b[32:63]}
// Pure VALU cross-half exchange (replaces ds_bpermute-based __shfl_xor(x,32)).
__device__ __forceinline__ uint32x2 pswap(unsigned a, unsigned b) {
  return __builtin_amdgcn_permlane32_swap(a, b, false, false);
}

// ---------------- prep: weight fp32->bf16 (blocks 0..4095) + LN (4096..8191)
__global__ __launch_bounds__(256) void prep_kernel(
    const float* __restrict__ h, const float* __restrict__ w0,
    const float* __restrict__ w1, const float* __restrict__ w2,
    const float* __restrict__ w3, const float* __restrict__ lw,
    const float* __restrict__ lb, unsigned short* __restrict__ Wcat,
    unsigned short* __restrict__ hn) {
  if (blockIdx.x < 4096) {
    int wsel = blockIdx.x >> 10;
    const float* s = (wsel == 0) ? w0 : (wsel == 1) ? w1 : (wsel == 2) ? w2 : w3;
    unsigned short* d = Wcat + ((size_t)wsel << 20);
    int i = ((blockIdx.x & 1023) << 8) + threadIdx.x;
    float4 v = reinterpret_cast<const float4*>(s)[i];
    ushort4 o;
    o.x = f2bf(v.x); o.y = f2bf(v.y); o.z = f2bf(v.z); o.w = f2bf(v.w);
    reinterpret_cast<ushort4*>(d)[i] = o;
    return;
  }
  int row = blockIdx.x - 4096;
  const float* x = h + (size_t)row * D_MODEL;
  float4 v = reinterpret_cast<const float4*>(x)[threadIdx.x];
  float s  = v.x + v.y + v.z + v.w;
  float s2 = v.x * v.x + v.y * v.y + v.z * v.z + v.w * v.w;
  for (int m = 1; m < 64; m <<= 1) {
    s  += __shfl_xor(s, m);
    s2 += __shfl_xor(s2, m);
  }
  __shared__ float ls[4], ls2[4];
  int wave = threadIdx.x >> 6;
  if ((threadIdx.x & 63) == 0) { ls[wave] = s; ls2[wave] = s2; }
  __syncthreads();
  s  = ls[0] + ls[1] + ls[2] + ls[3];
  s2 = ls2[0] + ls2[1] + ls2[2] + ls2[3];
  float mu  = s * (1.0f / D_MODEL);
  float var = s2 * (1.0f / D_MODEL) - mu * mu;
  float rs  = rsqrtf(var + LN_EPS);
  float4 wv = reinterpret_cast<const float4*>(lw)[threadIdx.x];
  float4 bv = reinterpret_cast<const float4*>(lb)[threadIdx.x];
  ushort4 o;
  o.x = f2bf((v.x - mu) * rs * wv.x + bv.x);
  o.y = f2bf((v.y - mu) * rs * wv.y + bv.y);
  o.z = f2bf((v.z - mu) * rs * wv.z + bv.z);
  o.w = f2bf((v.w - mu) * rs * wv.w + bv.w);
  reinterpret_cast<ushort4*>(hn + (size_t)row * D_MODEL)[threadIdx.x] = o;
}

// ---------------- fused QKV GEMM: [4096,1024] @ [3072,1024]^T -------------
// R8: BM=128 BN=96 BK=64, 512 thr (8 waves, wave tile 32x48), double-
// buffered LDS = 56 KB -> 2 blocks/CU co-resident: while one block sits in
// its vmcnt(0)+barrier drain, the other feeds the MFMA pipe (the R2 attn
// occupancy mechanism, applied to the GEMM). Grid (32,32) = 1024 blocks =
// exactly 2 clean generations at 2/CU; 1024%8==0 keeps XCD swizzle bijective.
__global__ __launch_bounds__(512, 2) void gemm_qkv_kernel(
    const unsigned short* __restrict__ A, const unsigned short* __restrict__ Wcat,
    const float* __restrict__ bq, const float* __restrict__ bk,
    const float* __restrict__ bv,
    unsigned short* __restrict__ QK, unsigned short* __restrict__ VtG) {
  __shared__ unsigned short As[2][128 * 64];  // 32 KB
  __shared__ unsigned short Bs[2][96 * 64];   // 24 KB

  const int tid  = threadIdx.x;
  const int w    = tid >> 6;        // 0..7
  const int lane = tid & 63;
  const int l15  = lane & 15;
  const int quad = lane >> 4;
  const int sw   = l15 & 7;
  const int wrow = (w >> 1) * 32;   // 0,32,64,96
  const int wcol = (w & 1) * 48;    // 0,48

  // XCD-aware bijective swizzle (1024 blocks = 8 XCDs x 128 contiguous)
  const int flat  = blockIdx.x + (blockIdx.y << 5);
  const int swzid = ((flat & 7) << 7) + (flat >> 3);
  const int bm = (swzid >> 5) * 128;   // 32 M-blocks
  const int bn = (swzid & 31) * 96;    // 32 N-blocks

  const int srow = tid >> 3;                        // 0..63
  const int swzc = (((tid & 7) ^ (srow & 7)) * 8);  // swizzled source granule
  const unsigned short* ga = A    + (size_t)(bm + srow) * 1024 + swzc;
  const unsigned short* gb = Wcat + (size_t)(bn + srow) * 1024 + swzc;

  floatx4 acc[2][3];
#pragma unroll
  for (int i = 0; i < 2; ++i)
#pragma unroll
    for (int j = 0; j < 3; ++j) acc[i][j] = {0.f, 0.f, 0.f, 0.f};

  // staging: one 512-thr round = 64 rows (4096 shorts). A: 2 rounds.
  // B: 1 full round + half round (rows 64..95, waves 0-3 only).
  auto stage = [&](int k0, int b) {
    unsigned short* asl = &As[b][0] + w * 512;
#pragma unroll
    for (int i = 0; i < 2; ++i) cp16(asl + i * 4096, ga + (size_t)i * 64 * 1024 + k0);
    cp16(&Bs[b][0] + w * 512, gb + k0);
    if (w < 4) cp16(&Bs[b][0] + 4096 + w * 512, gb + (size_t)64 * 1024 + k0);
  };

  stage(0, 0);

  for (int t = 0; t < 16; ++t) {
    __syncthreads();                       // tile t staged, tile t-1 reads done
    if (t + 1 < 16) stage((t + 1) * 64, (t + 1) & 1);   // overlap with compute
    const unsigned short* Ab = &As[t & 1][0];
    const unsigned short* Bb = &Bs[t & 1][0];
#pragma unroll
    for (int kb = 0; kb < 2; ++kb) {
      bf16x8 af[2], bfr[3];
#pragma unroll
      for (int mi = 0; mi < 2; ++mi)
        af[mi] = *reinterpret_cast<const bf16x8*>(
            Ab + (wrow + mi * 16 + l15) * 64 + (((kb * 4 + quad) ^ sw) * 8));
#pragma unroll
      for (int ni = 0; ni < 3; ++ni)
        bfr[ni] = *reinterpret_cast<const bf16x8*>(
            Bb + (wcol + ni * 16 + l15) * 64 + (((kb * 4 + quad) ^ sw) * 8));
#pragma unroll
      for (int mi = 0; mi < 2; ++mi)
#pragma unroll
        for (int ni = 0; ni < 3; ++ni)
          acc[mi][ni] = __builtin_amdgcn_mfma_f32_16x16x32_bf16(af[mi], bfr[ni], acc[mi][ni], 0, 0, 0);
    }
  }

  // epilogue: per-16-col fragment Q/K/V select (wave-uniform; 16-col frags
  // never straddle the 1024 boundaries since 1024 % 16 == 0)
#pragma unroll
  for (int mi = 0; mi < 2; ++mi) {
    const int row0 = bm + wrow + mi * 16 + quad * 4;
#pragma unroll
    for (int ni = 0; ni < 3; ++ni) {
      const int cb  = bn + wcol + ni * 16;   // uniform per (wave, ni)
      const int col = cb + l15;
      if (cb < 1024) {
        float bb = bq[col];
#pragma unroll
        for (int r = 0; r < 4; ++r)
          QK[(size_t)(row0 + r) * 2048 + col] = f2bf((acc[mi][ni][r] + bb) * QSCALE);
      } else if (cb < 2048) {
        float bb = bk[col - 1024];
#pragma unroll
        for (int r = 0; r < 4; ++r)
          QK[(size_t)(row0 + r) * 2048 + col] = f2bf(acc[mi][ni][r] + bb);
      } else {
        int d = col - 2048;
        float bb = bv[d];
        ushort4 o;
        o.x = f2bf(acc[mi][ni][0] + bb);
        o.y = f2bf(acc[mi][ni][1] + bb);
        o.z = f2bf(acc[mi][ni][2] + bb);
        o.w = f2bf(acc[mi][ni][3] + bb);
        *reinterpret_cast<ushort4*>(VtG + (size_t)d * 4096 + row0) = o;
      }
    }
  }
}

// ---------------- output GEMM: Obuf @ Wo^T + bo + resid -> fp32 -----------
// 2-phase prefetch (single barrier per K-step, double-buffered LDS).
__global__ __launch_bounds__(256) void gemm_out_kernel(
    const unsigned short* __restrict__ A, const unsigned short* __restrict__ Bt,
    const float* __restrict__ bo, const float* __restrict__ resid,
    float* __restrict__ out) {
  __shared__ unsigned short As[2][128 * 64];  // 32 KB
  __shared__ unsigned short Bs[2][64 * 64];   // 16 KB

  const int tid  = threadIdx.x;
  const int w    = tid >> 6;
  const int lane = tid & 63;
  const int l15  = lane & 15;
  const int quad = lane >> 4;
  const int sw   = l15 & 7;
  const int wm = (w >> 1) * 64;
  const int wn = (w & 1) * 32;
  const int bm = blockIdx.y * 128;
  const int bn = blockIdx.x * 64;

  const int srow = tid >> 3;
  const int swzc = (((tid & 7) ^ (srow & 7)) * 8);
  const unsigned short* ga = A  + (size_t)(bm + srow) * 1024 + swzc;
  const unsigned short* gb = Bt + (size_t)(bn + srow) * 1024 + swzc;

  floatx4 acc[4][2];
  for (int i = 0; i < 4; ++i)
    for (int j = 0; j < 2; ++j) acc[i][j] = {0.f, 0.f, 0.f, 0.f};

  auto stage = [&](int k0, int b) {
    unsigned short* asl = &As[b][0] + w * 512;
    unsigned short* bsl = &Bs[b][0] + w * 512;
#pragma unroll
    for (int i = 0; i < 4; ++i) cp16(asl + i * 2048, ga + (size_t)i * 32 * 1024 + k0);
#pragma unroll
    for (int i = 0; i < 2; ++i) cp16(bsl + i * 2048, gb + (size_t)i * 32 * 1024 + k0);
  };

  stage(0, 0);

  for (int t = 0; t < 16; ++t) {
    __syncthreads();                      // tile t staged, tile t-1 reads done
    if (t + 1 < 16) stage((t + 1) * 64, (t + 1) & 1);  // overlap with compute
    const unsigned short* Ab = &As[t & 1][0];
    const unsigned short* Bb = &Bs[t & 1][0];
#pragma unroll
    for (int kb = 0; kb < 2; ++kb) {
      bf16x8 af[4], bfr[2];
#pragma unroll
      for (int mi = 0; mi < 4; ++mi)
        af[mi] = *reinterpret_cast<const bf16x8*>(
            Ab + (wm + mi * 16 + l15) * 64 + (((kb * 4 + quad) ^ sw) * 8));
#pragma unroll
      for (int ni = 0; ni < 2; ++ni)
        bfr[ni] = *reinterpret_cast<const bf16x8*>(
            Bb + (wn + ni * 16 + l15) * 64 + (((kb * 4 + quad) ^ sw) * 8));
#pragma unroll
      for (int mi = 0; mi < 4; ++mi)
#pragma unroll
        for (int ni = 0; ni < 2; ++ni)
          acc[mi][ni] = __builtin_amdgcn_mfma_f32_16x16x32_bf16(af[mi], bfr[ni], acc[mi][ni], 0, 0, 0);
    }
  }

#pragma unroll
  for (int mi = 0; mi < 4; ++mi)
#pragma unroll
    for (int ni = 0; ni < 2; ++ni) {
      int col = bn + wn + ni * 16 + l15;
      float bb = bo[col];
#pragma unroll
      for (int r = 0; r < 4; ++r) {
        int row = bm + wm + mi * 16 + quad * 4 + r;
        size_t idx = (size_t)row * 1024 + col;
        out[idx] = acc[mi][ni][r] + bb + resid[idx];
      }
    }
}

// ---------------- flash attention: grid (H, S/128, B), 512 thr ------------
// R4 structure (proven best 46.7 us): 8-wave, 2-way key split, permlane32
// cross-half exchanges, additive combine, pk_add row-sum tree. R7's setprio
// reverted (measured -1.2 us; lockstep barriers give it nothing to arbitrate).
__global__ __launch_bounds__(512, 4) void attn_kernel(
    const unsigned short* __restrict__ QK, const unsigned short* __restrict__ VtG,
    unsigned short* __restrict__ O) {
  __shared__ unsigned short Ks[2][128 * 64];  // [key][d]  swizzled
  __shared__ unsigned short Vs[2][64 * 128];  // [d][key]  swizzled

  const int tid  = threadIdx.x;
  const int w    = tid >> 6;     // 0..7
  const int wq   = w & 3;        // q sub-tile
  const int kb0  = (w >> 2) * 2; // key-half: kb in {kb0, kb0+1}
  const int lane = tid & 63;
  const int l31  = lane & 31;
  const int h    = lane >> 5;
  const int rsw  = (l31 & 7) ^ ((l31 >> 3) << 1);  // read swizzle

  const int hh = blockIdx.x, qt = blockIdx.y, bz = blockIdx.z;
  const int tq0  = bz * SEQ + qt * 128;
  const int hoff = hh * 64;

  // Q B-frags: n=q=lane&31, k = kd*16 + h*8 + j
  bf16x8 qf[4];
  {
    const unsigned short* qp =
        QK + (size_t)(tq0 + wq * 32 + l31) * 2048 + hoff + h * 8;
#pragma unroll
    for (int kd = 0; kd < 4; ++kd)
      qf[kd] = *reinterpret_cast<const bf16x8*>(qp + kd * 16);
  }

  floatx16 oacc[2];
#pragma unroll
  for (int db = 0; db < 2; ++db)
#pragma unroll
    for (int r = 0; r < 16; ++r) oacc[db][r] = 0.f;
  float lsum = 0.f;

  // staging addresses (512 threads: K rows tid>>3 in 0..63, V rows tid>>4 in 0..31)
  const unsigned short* kg = QK + 1024 + hoff
      + (size_t)(bz * SEQ + (tid >> 3)) * 2048
      + (((tid & 7) ^ ((tid >> 3) & 7) ^ ((w & 3) << 1)) * 8);
  const unsigned short* vg = VtG
      + (size_t)(hoff + (tid >> 4)) * 4096 + bz * SEQ
      + (((tid & 15) ^ ((tid >> 4) & 7) ^ (((w >> 1) & 3) << 1)) * 8);

  auto stage = [&](int kt, int b) {
    const unsigned short* kgi = kg + (size_t)(kt * 128) * 2048;
    const unsigned short* vgi = vg + kt * 128;
    unsigned short* ksl = Ks[b] + w * 512;
    unsigned short* vsl = Vs[b] + w * 512;
#pragma unroll
    for (int i = 0; i < 2; ++i) cp16(ksl + i * 4096, kgi + (size_t)(i * 64) * 2048);
#pragma unroll
    for (int i = 0; i < 2; ++i) cp16(vsl + i * 4096, vgi + (size_t)(i * 32) * 4096);
  };

  stage(0, 0);

  for (int kt = 0; kt < SEQ / 128; ++kt) {
    __syncthreads();
    if (kt + 1 < SEQ / 128) stage(kt + 1, (kt + 1) & 1);
    const unsigned short* Kb = Ks[kt & 1];
    const unsigned short* Vb = Vs[kt & 1];

    // S^T for this wave's 2 key-blocks of 32, K-dim 4 chunks of 16
    floatx16 ss[2];
#pragma unroll
    for (int kk = 0; kk < 2; ++kk)
#pragma unroll
      for (int r = 0; r < 16; ++r) ss[kk][r] = 0.f;
#pragma unroll
    for (int kk = 0; kk < 2; ++kk) {
      const int kb = kb0 + kk;
      const unsigned short* krow = Kb + (kb * 32 + l31) * 64;
#pragma unroll
      for (int kd = 0; kd < 4; ++kd) {
        bf16x8 kf = *reinterpret_cast<const bf16x8*>(
            krow + (((kd * 2 + h) ^ rsw) * 8));
        ss[kk] = __builtin_amdgcn_mfma_f32_32x32x16_bf16(kf, qf[kd], ss[kk], 0, 0, 0);
      }
    }

    // per key-block: exp2, row-sum, build PV B-frags in-register, PV MFMAs
#pragma unroll
    for (int kk = 0; kk < 2; ++kk) {
      const int kb = kb0 + kk;
      float e[16];
#pragma unroll
      for (int r = 0; r < 16; ++r) e[r] = __builtin_amdgcn_exp2f(ss[kk][r]);
      // packed row-sum tree: 7 v_pk_add_f32 + 1 scalar add
      floatx2 a0 = {e[0], e[1]},   a1 = {e[2], e[3]},
              a2 = {e[4], e[5]},   a3 = {e[6], e[7]},
              a4 = {e[8], e[9]},   a5 = {e[10], e[11]},
              a6 = {e[12], e[13]}, a7 = {e[14], e[15]};
      floatx2 b0 = a0 + a1, b1 = a2 + a3, b2 = a4 + a5, b3 = a6 + a7;
      floatx2 c0 = b0 + b1, c1 = b2 + b3;
      floatx2 d2 = c0 + c1;
      float bs = d2.x + d2.y;
      {  // cross-half row-sum: bs += bs[lane^32], via permlane (no LDS)
        union { float f; unsigned u; } bu; bu.f = bs;
        uint32x2 br = pswap(bu.u, bu.u);
        union { unsigned u; float f; } b0u, b1u;
        b0u.u = br.x; b1u.u = br.y;
        bs = b0u.f + b1u.f;
      }
      lsum += bs;
      unsigned p[8];
#pragma unroll
      for (int i = 0; i < 8; ++i) p[i] = pk2bf(e[2 * i + 1], e[2 * i]);

#pragma unroll
      for (int sub = 0; sub < 2; ++sub) {
        uint32x2 r0 = pswap(p[sub * 4 + 0], p[sub * 4 + 2]);
        uint32x2 r1 = pswap(p[sub * 4 + 1], p[sub * 4 + 3]);
        union { unsigned u[4]; bf16x8 v; } pf;
        pf.u[0] = r0.x;
        pf.u[1] = r1.x;
        pf.u[2] = r0.y;
        pf.u[3] = r1.y;
#pragma unroll
        for (int db = 0; db < 2; ++db) {
          bf16x8 vf = *reinterpret_cast<const bf16x8*>(
              Vb + (db * 32 + l31) * 128 + (((kb * 4 + sub * 2 + h) ^ rsw) * 8));
          oacc[db] = __builtin_amdgcn_mfma_f32_32x32x16_bf16(vf, pf.v, oacc[db], 0, 0, 0);
        }
      }
    }
  }

  // ---- combine the two key-halves (additive: no max tracking) ----
  __syncthreads();  // all waves done reading K/V LDS
  float* osc = (float*)&Ks[0][0];  // 32 KB: [wq][lane][32] bank-rotated
  float* lsc = (float*)&Vs[0][0];  // 1 KB:  [wq][lane]
  if (w >= 4) {
    float* dst = osc + ((size_t)(wq * 64 + lane) * 32);
#pragma unroll
    for (int db = 0; db < 2; ++db)
#pragma unroll
      for (int r = 0; r < 16; ++r)
        dst[(db * 16 + r + lane) & 31] = oacc[db][r];
    lsc[wq * 64 + lane] = lsum;
  }
  __syncthreads();
  if (w < 4) {
    const float* src = osc + ((size_t)(wq * 64 + lane) * 32);
    lsum += lsc[wq * 64 + lane];
#pragma unroll
    for (int db = 0; db < 2; ++db)
#pragma unroll
      for (int r = 0; r < 16; ++r)
        oacc[db][r] += src[(db * 16 + r + lane) & 31];

    // finalize: lane holds O[q=wq*32+l31][d = db*32 + (r&3)+8*(r>>2)+4*h]
    float inv = 1.0f / lsum;
    unsigned short* ob = O + (size_t)(tq0 + wq * 32 + l31) * 1024 + hoff;
#pragma unroll
    for (int db = 0; db < 2; ++db)
#pragma unroll
      for (int rg = 0; rg < 4; ++rg) {
        int d0 = db * 32 + rg * 8 + h * 4;
        uint2 ov;
        ov.x = pk2bf(oacc[db][rg * 4 + 1] * inv, oacc[db][rg * 4 + 0] * inv);
        ov.y = pk2bf(oacc[db][rg * 4 + 3] * inv, oacc[db][rg * 4 + 2] * inv);
        *reinterpret_cast<uint2*>(ob + d0) = ov;
      }
  }
}

// ---------------- launch ---------------------------------------------------
extern "C" void kernel_launch(void* const* d_in, const int* in_sizes, int n_in,
                              void* d_out, int out_size, void* d_ws, size_t ws_size,
                              hipStream_t stream) {
  const float* h    = (const float*)d_in[0];
  const float* Wq   = (const float*)d_in[1];
  const float* bq   = (const float*)d_in[2];
  const float* Wk   = (const float*)d_in[3];
  const float* bk   = (const float*)d_in[4];
  const float* Wv   = (const float*)d_in[5];
  const float* bv   = (const float*)d_in[6];
  const float* Wo   = (const float*)d_in[7];
  const float* bo   = (const float*)d_in[8];
  const float* ln_w = (const float*)d_in[9];
  const float* ln_b = (const float*)d_in[10];
  float* out = (float*)d_out;

  unsigned short* ws = (unsigned short*)d_ws;
  const size_t WSZ = (size_t)1 << 20;
  unsigned short* Wcat = ws;                       // 4M shorts: Wq|Wk|Wv|Wo
  unsigned short* hn   = Wcat + 4 * WSZ;           // [4096][1024]
  unsigned short* QKb  = hn + (size_t)TOKENS * D_MODEL;        // [4096][2048]
  unsigned short* VtG  = QKb + (size_t)TOKENS * 2048;          // [1024][4096]
  unsigned short* Obuf = VtG + (size_t)D_MODEL * TOKENS;       // [4096][1024]

  prep_kernel<<<8192, 256, 0, stream>>>(h, Wq, Wk, Wv, Wo, ln_w, ln_b, Wcat, hn);

  gemm_qkv_kernel<<<dim3(32, 32), 512, 0, stream>>>(hn, Wcat, bq, bk, bv, QKb, VtG);

  attn_kernel<<<dim3(N_HEADS, SEQ / 128, BATCH), 512, 0, stream>>>(QKb, VtG, Obuf);

  gemm_out_kernel<<<dim3(16, 32), 256, 0, stream>>>(Obuf, Wcat + 3 * WSZ, bo, h, out);
}